// Round 6
// baseline (114.019 us; speedup 1.0000x reference)
//
#include <hip/hip_runtime.h>
#include <math.h>

// ---------------------------------------------------------------------------
// BiMultiHeadAttention fused pipeline (MI355X / gfx950)
//   B=4 N=2048 E=256 H=8 D=32   (bh = B*H = 32 heads total)
//
// Round 6:
//   - attn: wave stagger (qi-parity reverses tile order) + dual accumulators
//     -> LDS pipe and VALU pipe overlap across waves; setprio on MFMA pairs
//   - qkv_gemm: A operand register-direct from L2 (1-step prefetch), At LDS gone
//   - proj_ln: all-8 A-fragments prefetched to regs; Bt staged issue-early/
//     write-late (T14); At LDS gone
// ---------------------------------------------------------------------------

typedef __attribute__((ext_vector_type(8))) short short8;   // 8 bf16 (4 VGPR)
typedef __attribute__((ext_vector_type(4))) float f32x4;
typedef __attribute__((ext_vector_type(16))) float f32x16;
typedef __attribute__((ext_vector_type(4))) unsigned short u16x4;

union FragU { unsigned int u[4]; short8 s8; };

__device__ __forceinline__ unsigned short bf16_rn(float f) {
    union { float f; unsigned int u; } c; c.f = f;
    return (unsigned short)((c.u + 0x7FFFu + ((c.u >> 16) & 1u)) >> 16);
}
__device__ __forceinline__ float b2f(unsigned short u) {
    union { unsigned int i; float f; } c; c.i = ((unsigned int)u) << 16;
    return c.f;
}

#if __has_builtin(__builtin_amdgcn_exp2f)
__device__ __forceinline__ float fexp2(float x) { return __builtin_amdgcn_exp2f(x); }
#else
__device__ __forceinline__ float fexp2(float x) { return exp2f(x); }
#endif

__device__ __forceinline__ f32x4 mfma16(short8 a, short8 b, f32x4 c) {
    return __builtin_amdgcn_mfma_f32_16x16x32_bf16(a, b, c, 0, 0, 0);
}
__device__ __forceinline__ f32x16 mfma32(short8 a, short8 b, f32x16 c) {
    return __builtin_amdgcn_mfma_f32_32x32x16_bf16(a, b, c, 0, 0, 0);
}

__device__ __forceinline__ void plswap(unsigned int& x, unsigned int& y) {
    asm("v_permlane32_swap_b32 %0, %1" : "+v"(x), "+v"(y));
}

// S^T regs (k-local = (j&3)+8*(j>>2)+4*hi) packed as w[m]=(p[2m],p[2m+1]) ->
// one 16-row chunk of an MFMA operand fragment (contract elems hi*8+{0..7}).
__device__ __forceinline__ short8 pfrag(unsigned int w0, unsigned int w1,
                                        unsigned int w2, unsigned int w3) {
    plswap(w0, w2);
    plswap(w1, w3);
    FragU fu;
    fu.u[0] = w0; fu.u[1] = w1; fu.u[2] = w2; fu.u[3] = w3;
    return fu.s8;
}

// ---------------------------------------------------------------------------
// 1) merged prep: blocks [0,2048) convert x streams; [2048,3072) transpose W
// ---------------------------------------------------------------------------
__global__ void prep_all(const float* __restrict__ xl, const float* __restrict__ xr,
                         const float* __restrict__ Wq, const float* __restrict__ Wk,
                         const float* __restrict__ Wv, const float* __restrict__ Wp,
                         unsigned short* __restrict__ xlb, unsigned short* __restrict__ xrb,
                         unsigned short* __restrict__ xdb,
                         unsigned short* __restrict__ Wqt, unsigned short* __restrict__ Wkt,
                         unsigned short* __restrict__ Wvt, unsigned short* __restrict__ Wpt) {
    const int bid = blockIdx.x;
    if (bid < 2048) {
        const size_t i = ((size_t)bid * 256 + threadIdx.x) * 4;
        const float4 A = *(const float4*)(xl + i);
        const float4 Bv = *(const float4*)(xr + i);
        u16x4 pa = { bf16_rn(A.x), bf16_rn(A.y), bf16_rn(A.z), bf16_rn(A.w) };
        u16x4 pb = { bf16_rn(Bv.x), bf16_rn(Bv.y), bf16_rn(Bv.z), bf16_rn(Bv.w) };
        u16x4 pd = { bf16_rn(A.x - Bv.x), bf16_rn(A.y - Bv.y),
                     bf16_rn(A.z - Bv.z), bf16_rn(A.w - Bv.w) };
        *(u16x4*)(xlb + i) = pa;
        *(u16x4*)(xrb + i) = pb;
        *(u16x4*)(xdb + i) = pd;
    } else {
        const int gid = (bid - 2048) * 256 + threadIdx.x;   // 0 .. 262143
        const int m = gid >> 16;
        const int idx = gid & 65535;
        const int k = idx >> 8, n = idx & 255;
        const float* W = (m == 0) ? Wq : (m == 1) ? Wk : (m == 2) ? Wv : Wp;
        unsigned short* Wt = (m == 0) ? Wqt : (m == 1) ? Wkt : (m == 2) ? Wvt : Wpt;
        Wt[n * 256 + k] = bf16_rn(W[(size_t)k * 256 + n]);
    }
}

// ---------------------------------------------------------------------------
// 2) QKV projection GEMM: [8192,256] x [256,256] + bias, 3 outputs (z-dim)
//    A register-direct (1-step prefetch), Bt dbuf in LDS
// ---------------------------------------------------------------------------
__launch_bounds__(256)
__global__ void qkv_gemm(const unsigned short* __restrict__ xlb,
                         const unsigned short* __restrict__ xrb,
                         const unsigned short* __restrict__ xdb,
                         const unsigned short* __restrict__ Wqt,
                         const unsigned short* __restrict__ Wkt,
                         const unsigned short* __restrict__ Wvt,
                         const float* __restrict__ bq, const float* __restrict__ bk,
                         const float* __restrict__ bv,
                         unsigned short* __restrict__ Qg, unsigned short* __restrict__ Kg,
                         unsigned short* __restrict__ Vtg) {
    const int z = blockIdx.z;
    const unsigned short* A  = (z == 0) ? xlb : (z == 1) ? xrb : xdb;
    const unsigned short* Wt = (z == 0) ? Wqt : (z == 1) ? Wkt : Wvt;
    const float* bias        = (z == 0) ? bq  : (z == 1) ? bk  : bv;

    __shared__ unsigned short Bt[2][64][40];

    const int tid = threadIdx.x;
    const int lane = tid & 63, wv = tid >> 6;
    const int a = lane & 15, g = lane >> 4;
    const int wr = wv >> 1, wc = wv & 1;
    const int r0 = blockIdx.x * 128;
    const int c0 = blockIdx.y * 64;

    const f32x4 fz = {0.f, 0.f, 0.f, 0.f};
    f32x4 acc[4][2];
#pragma unroll
    for (int f = 0; f < 4; ++f)
#pragma unroll
        for (int t = 0; t < 2; ++t) acc[f][t] = fz;

    const int brow = tid >> 2, boff = (tid & 3) * 8;
    const unsigned short* bsrc = Wt + (size_t)(c0 + brow) * 256 + boff;
    const unsigned short* abase = A + (size_t)(r0 + wr * 64 + a) * 256 + g * 8;

    short8 afA[4], afB[4];
#pragma unroll
    for (int f = 0; f < 4; ++f) afA[f] = *(const short8*)(abase + f * 16 * 256);
    *(short8*)&Bt[0][brow][boff] = *(const short8*)bsrc;
    __syncthreads();

#pragma unroll
    for (int ks = 0; ks < 8; ++ks) {
        const int b = ks & 1;
        const short8* afc = (ks & 1) ? afB : afA;
        short8* afn = (ks & 1) ? afA : afB;
        if (ks < 7) {
            *(short8*)&Bt[b ^ 1][brow][boff] = *(const short8*)(bsrc + (ks + 1) * 32);
#pragma unroll
            for (int f = 0; f < 4; ++f)
                afn[f] = *(const short8*)(abase + f * 16 * 256 + (ks + 1) * 32);
        }
        short8 bfr[2];
#pragma unroll
        for (int t = 0; t < 2; ++t) bfr[t] = *(const short8*)&Bt[b][wc * 32 + t * 16 + a][g * 8];
#pragma unroll
        for (int f = 0; f < 4; ++f)
#pragma unroll
            for (int t = 0; t < 2; ++t) acc[f][t] = mfma16(afc[f], bfr[t], acc[f][t]);
        __syncthreads();
    }

    const float scq = 0.17677669529663687f * 1.4426950408889634f;
#pragma unroll
    for (int t = 0; t < 2; ++t) {
        const int C = c0 + wc * 32 + t * 16 + a;
        const float bb = bias[C];
        const int h = C >> 5, d = C & 31;
#pragma unroll
        for (int f = 0; f < 4; ++f) {
            const int Rb = r0 + wr * 64 + f * 16 + g * 4;
            const int b_ = Rb >> 11, n = Rb & 2047;
            const int bhh = b_ * 8 + h;
            float v[4];
#pragma unroll
            for (int r = 0; r < 4; ++r) {
                v[r] = acc[f][t][r] + bb;
                if (z == 0) v[r] *= scq;
            }
            if (z < 2) {
                unsigned short* dst = ((z == 0) ? Qg : Kg) + (size_t)(bhh * 2048 + n) * 32 + d;
#pragma unroll
                for (int r = 0; r < 4; ++r) dst[(size_t)r * 32] = bf16_rn(v[r]);
            } else {
                u16x4 pk = { bf16_rn(v[0]), bf16_rn(v[1]), bf16_rn(v[2]), bf16_rn(v[3]) };
                *(u16x4*)(Vtg + (size_t)(bhh * 32 + d) * 2048 + n) = pk;
            }
        }
    }
}

// ---------------------------------------------------------------------------
// 3) pass 1: flash attention (exp2 domain, no shift) -> out_l + Vs = V/l
//    8 waves: qi (q-subtile), z (k-half). Staggered tile order + dual acc.
// ---------------------------------------------------------------------------
#define P1_TILE(SB, ACC, LRUN)                                                  \
    {                                                                           \
        const short8 ck0 = *(const short8*)((SB) + ro);                         \
        const short8 ck1 = *(const short8*)((SB) + 512 + ro);                   \
        const short8 cv0 = *(const short8*)((SB) + 1024 + ro);                  \
        const short8 cv1 = *(const short8*)((SB) + 1536 + ro);                  \
        __builtin_amdgcn_s_setprio(1);                                          \
        f32x16 s = {};                                                          \
        s = mfma32(ck0, qf0, s);                                                \
        s = mfma32(ck1, qf1, s);                                                \
        __builtin_amdgcn_s_setprio(0);                                          \
        float p[16];                                                            \
        _Pragma("unroll") for (int j = 0; j < 16; ++j) p[j] = fexp2(s[j]);      \
        LRUN += (((p[0] + p[1]) + (p[2] + p[3])) + ((p[4] + p[5]) + (p[6] + p[7]))) \
              + (((p[8] + p[9]) + (p[10] + p[11])) + ((p[12] + p[13]) + (p[14] + p[15]))); \
        unsigned int w[8];                                                      \
        _Pragma("unroll") for (int mm = 0; mm < 8; ++mm)                        \
            asm("v_cvt_pk_bf16_f32 %0, %1, %2"                                  \
                : "=v"(w[mm]) : "v"(p[2 * mm]), "v"(p[2 * mm + 1]));            \
        __builtin_amdgcn_s_setprio(1);                                          \
        ACC = mfma32(cv0, pfrag(w[0], w[1], w[2], w[3]), ACC);                  \
        ACC = mfma32(cv1, pfrag(w[4], w[5], w[6], w[7]), ACC);                  \
        __builtin_amdgcn_s_setprio(0);                                          \
    }

__launch_bounds__(512, 4)
__global__ void attn_pass1(const unsigned short* __restrict__ Qg,
                           const unsigned short* __restrict__ Kg,
                           const unsigned short* __restrict__ Vtg,
                           unsigned short* __restrict__ AOl,
                           unsigned short* __restrict__ Vsg) {
    __shared__ unsigned short ST[2][2][2][2][2][64][8];  // [z][pbuf][sub][kv][c][slot][e] 32KB
    __shared__ float accS[4][16][64];                    // 16KB
    __shared__ float lsumS[4][64];                       // 1KB

    const int f = blockIdx.x;
    const int bh = 4 * (f & 7) + (f >> 7);
    const int qblk = (f >> 3) & 15;
    const int tid = threadIdx.x;
    const int wv = tid >> 6;
    const int qi = wv & 3, z = wv >> 2;
    const int lane = tid & 63, l31 = lane & 31, hi = lane >> 5;
    const int q0 = qblk * 128 + qi * 32;

    const unsigned short* Qb = Qg + (size_t)bh * 2048 * 32;
    const unsigned short* Kb = Kg + (size_t)bh * 2048 * 32;
    const unsigned short* Vb = Vtg + (size_t)bh * 32 * 2048;

    const short8 qf0 = *(const short8*)(Qb + (size_t)(q0 + l31) * 32 + hi * 8);
    const short8 qf1 = *(const short8*)(Qb + (size_t)(q0 + l31) * 32 + 16 + hi * 8);

    // staging geometry: qi<2 -> K rows, qi>=2 -> V rows (16 rows per wave)
    const int kv = qi >> 1;
    const int srow = (qi & 1) * 16 + (lane >> 2);
    const int m = lane & 3;
    unsigned short* wp00 = &ST[z][0][0][kv][m >> 1][srow + 32 * (m & 1)][0];
    unsigned short* wp01 = &ST[z][0][1][kv][m >> 1][srow + 32 * (m & 1)][0];
    unsigned short* wp10 = &ST[z][1][0][kv][m >> 1][srow + 32 * (m & 1)][0];
    unsigned short* wp11 = &ST[z][1][1][kv][m >> 1][srow + 32 * (m & 1)][0];
    const size_t gstep = kv ? 32 : 1024;               // per-tile element step
    const unsigned short* sgb = kv
        ? Vb + (size_t)srow * 2048 + m * 8
        : Kb + (size_t)srow * 32 + m * 8;
    const int zt = z * 32;

    const unsigned short* rb00 = &ST[z][0][0][0][0][0][0];
    const unsigned short* rb01 = &ST[z][0][1][0][0][0][0];
    const unsigned short* rb10 = &ST[z][1][0][0][0][0][0];
    const unsigned short* rb11 = &ST[z][1][1][0][0][0][0];
    const int ro = (l31 + 32 * hi) * 8;

    f32x16 accA = {}, accB = {};
    float l_runA = 0.f, l_runB = 0.f;

    // prologue: tiles 0,1 -> pbuf0; tiles 2,3 -> regs
    short8 rr0 = *(const short8*)(sgb + (size_t)(zt + 0) * gstep);
    short8 rr1 = *(const short8*)(sgb + (size_t)(zt + 1) * gstep);
    *(short8*)wp00 = rr0;
    *(short8*)wp01 = rr1;
    rr0 = *(const short8*)(sgb + (size_t)(zt + 2) * gstep);
    rr1 = *(const short8*)(sgb + (size_t)(zt + 3) * gstep);
    __syncthreads();

#pragma unroll
    for (int ph = 0; ph < 16; ++ph) {
        const int pb = ph & 1;
        unsigned short* wA = pb ? wp00 : wp10;
        unsigned short* wB = pb ? wp01 : wp11;
        const unsigned short* rA = pb ? rb10 : rb00;
        const unsigned short* rB = pb ? rb11 : rb01;
        if (ph < 15) { *(short8*)wA = rr0; *(short8*)wB = rr1; }
        if (ph < 14) {
            rr0 = *(const short8*)(sgb + (size_t)(zt + 2 * ph + 4) * gstep);
            rr1 = *(const short8*)(sgb + (size_t)(zt + 2 * ph + 5) * gstep);
        }
        if (qi & 1) {               // stagger: odd waves take tile B first
            P1_TILE(rB, accB, l_runB)
            P1_TILE(rA, accA, l_runA)
        } else {
            P1_TILE(rA, accA, l_runA)
            P1_TILE(rB, accB, l_runB)
        }
        __syncthreads();
    }

    f32x16 acc;
#pragma unroll
    for (int j = 0; j < 16; ++j) acc[j] = accA[j] + accB[j];
    const float l_run = l_runA + l_runB;
    float lsum = l_run + __shfl_xor(l_run, 32);

    if (z == 1) {
#pragma unroll
        for (int j = 0; j < 16; ++j) accS[qi][j][lane] = acc[j];
        lsumS[qi][lane] = lsum;
    }
    __syncthreads();
    if (z == 0) {
        lsum += lsumS[qi][lane];
        const float rl = 1.0f / lsum;
#pragma unroll
        for (int j = 0; j < 16; ++j) acc[j] += accS[qi][j][lane];

        const int b_ = bh >> 3, h = bh & 7;
        const int q = q0 + l31;
        unsigned short* dst = AOl + (size_t)(b_ * 2048 + q) * 256 + h * 32;
#pragma unroll
        for (int g2 = 0; g2 < 4; ++g2) {
            u16x4 pk = { bf16_rn(acc[4 * g2 + 0] * rl), bf16_rn(acc[4 * g2 + 1] * rl),
                         bf16_rn(acc[4 * g2 + 2] * rl), bf16_rn(acc[4 * g2 + 3] * rl) };
            *(u16x4*)(dst + 8 * g2 + 4 * hi) = pk;
        }
        if (hi == 0) lsumS[qi][l31] = rl;   // rl for column q0+l31
    }
    __syncthreads();
    if (z == 1) {
        // scale V columns [q0, q0+32) by rl: lane (l31,hi) -> d=l31, 16 cols
        const int cb = hi * 16;
        float il[16];
#pragma unroll
        for (int e = 0; e < 16; e += 4) {
            const float4 v4 = *(const float4*)&lsumS[qi][cb + e];
            il[e] = v4.x; il[e + 1] = v4.y; il[e + 2] = v4.z; il[e + 3] = v4.w;
        }
        const unsigned short* vsrc = Vb + (size_t)l31 * 2048 + q0 + cb;
        unsigned short* vdst = Vsg + (size_t)bh * 32 * 2048 + (size_t)l31 * 2048 + q0 + cb;
#pragma unroll
        for (int c4 = 0; c4 < 4; ++c4) {
            const u16x4 vv = *(const u16x4*)(vsrc + c4 * 4);
            u16x4 o = { bf16_rn(b2f(vv.x) * il[c4 * 4 + 0]),
                        bf16_rn(b2f(vv.y) * il[c4 * 4 + 1]),
                        bf16_rn(b2f(vv.z) * il[c4 * 4 + 2]),
                        bf16_rn(b2f(vv.w) * il[c4 * 4 + 3]) };
            *(u16x4*)(vdst + c4 * 4) = o;
        }
    }
}

// ---------------------------------------------------------------------------
// 4) pass 2: out_r = exp2(S)^T @ Vs  (Vs pre-normalized). Same structure.
// ---------------------------------------------------------------------------
#define P2_TILE(SB, ACC)                                                        \
    {                                                                           \
        const short8 cq0 = *(const short8*)((SB) + ro);                         \
        const short8 cq1 = *(const short8*)((SB) + 512 + ro);                   \
        const short8 cv0 = *(const short8*)((SB) + 1024 + ro);                  \
        const short8 cv1 = *(const short8*)((SB) + 1536 + ro);                  \
        __builtin_amdgcn_s_setprio(1);                                          \
        f32x16 s = {};                                                          \
        s = mfma32(cq0, kf0, s);                                                \
        s = mfma32(cq1, kf1, s);                                                \
        __builtin_amdgcn_s_setprio(0);                                          \
        float p[16];                                                            \
        _Pragma("unroll") for (int j = 0; j < 16; ++j) p[j] = fexp2(s[j]);      \
        unsigned int w[8];                                                      \
        _Pragma("unroll") for (int mm = 0; mm < 8; ++mm)                        \
            asm("v_cvt_pk_bf16_f32 %0, %1, %2"                                  \
                : "=v"(w[mm]) : "v"(p[2 * mm]), "v"(p[2 * mm + 1]));            \
        __builtin_amdgcn_s_setprio(1);                                          \
        ACC = mfma32(pfrag(w[0], w[1], w[2], w[3]), cv0, ACC);                  \
        ACC = mfma32(pfrag(w[4], w[5], w[6], w[7]), cv1, ACC);                  \
        __builtin_amdgcn_s_setprio(0);                                          \
    }

__launch_bounds__(512, 4)
__global__ void attn_pass2(const unsigned short* __restrict__ Qg,
                           const unsigned short* __restrict__ Kg,
                           const unsigned short* __restrict__ Vsg,
                           unsigned short* __restrict__ AOr) {
    __shared__ unsigned short ST[2][2][2][2][2][64][8];
    __shared__ float accS[4][16][64];

    const int f = blockIdx.x;
    const int bh = 4 * (f & 7) + (f >> 7);
    const int kblk = (f >> 3) & 15;
    const int tid = threadIdx.x;
    const int wv = tid >> 6;
    const int ki = wv & 3, z = wv >> 2;
    const int lane = tid & 63, l31 = lane & 31, hi = lane >> 5;
    const int k0 = kblk * 128 + ki * 32;

    const unsigned short* Qb = Qg + (size_t)bh * 2048 * 32;
    const unsigned short* Kb = Kg + (size_t)bh * 2048 * 32;
    const unsigned short* Vb = Vsg + (size_t)bh * 32 * 2048;

    const short8 kf0 = *(const short8*)(Kb + (size_t)(k0 + l31) * 32 + hi * 8);
    const short8 kf1 = *(const short8*)(Kb + (size_t)(k0 + l31) * 32 + 16 + hi * 8);

    const int kv = ki >> 1;
    const int srow = (ki & 1) * 16 + (lane >> 2);
    const int m = lane & 3;
    unsigned short* wp00 = &ST[z][0][0][kv][m >> 1][srow + 32 * (m & 1)][0];
    unsigned short* wp01 = &ST[z][0][1][kv][m >> 1][srow + 32 * (m & 1)][0];
    unsigned short* wp10 = &ST[z][1][0][kv][m >> 1][srow + 32 * (m & 1)][0];
    unsigned short* wp11 = &ST[z][1][1][kv][m >> 1][srow + 32 * (m & 1)][0];
    const size_t gstep = kv ? 32 : 1024;
    const unsigned short* sgb = kv
        ? Vb + (size_t)srow * 2048 + m * 8
        : Qb + (size_t)srow * 32 + m * 8;
    const int zt = z * 32;

    const unsigned short* rb00 = &ST[z][0][0][0][0][0][0];
    const unsigned short* rb01 = &ST[z][0][1][0][0][0][0];
    const unsigned short* rb10 = &ST[z][1][0][0][0][0][0];
    const unsigned short* rb11 = &ST[z][1][1][0][0][0][0];
    const int ro = (l31 + 32 * hi) * 8;

    f32x16 accA = {}, accB = {};

    short8 rr0 = *(const short8*)(sgb + (size_t)(zt + 0) * gstep);
    short8 rr1 = *(const short8*)(sgb + (size_t)(zt + 1) * gstep);
    *(short8*)wp00 = rr0;
    *(short8*)wp01 = rr1;
    rr0 = *(const short8*)(sgb + (size_t)(zt + 2) * gstep);
    rr1 = *(const short8*)(sgb + (size_t)(zt + 3) * gstep);
    __syncthreads();

#pragma unroll
    for (int ph = 0; ph < 16; ++ph) {
        const int pb = ph & 1;
        unsigned short* wA = pb ? wp00 : wp10;
        unsigned short* wB = pb ? wp01 : wp11;
        const unsigned short* rA = pb ? rb10 : rb00;
        const unsigned short* rB = pb ? rb11 : rb01;
        if (ph < 15) { *(short8*)wA = rr0; *(short8*)wB = rr1; }
        if (ph < 14) {
            rr0 = *(const short8*)(sgb + (size_t)(zt + 2 * ph + 4) * gstep);
            rr1 = *(const short8*)(sgb + (size_t)(zt + 2 * ph + 5) * gstep);
        }
        if (ki & 1) {
            P2_TILE(rB, accB)
            P2_TILE(rA, accA)
        } else {
            P2_TILE(rA, accA)
            P2_TILE(rB, accB)
        }
        __syncthreads();
    }

    f32x16 acc;
#pragma unroll
    for (int j = 0; j < 16; ++j) acc[j] = accA[j] + accB[j];

    if (z == 1) {
#pragma unroll
        for (int j = 0; j < 16; ++j) accS[ki][j][lane] = acc[j];
    }
    __syncthreads();
    if (z == 0) {
#pragma unroll
        for (int j = 0; j < 16; ++j) acc[j] += accS[ki][j][lane];

        const int b_ = bh >> 3, h = bh & 7;
#pragma unroll
        for (int j = 0; j < 16; ++j) {
            const int krow = k0 + (j & 3) + 8 * (j >> 2) + 4 * hi;
            AOr[(size_t)(b_ * 2048 + krow) * 256 + h * 32 + l31] = bf16_rn(acc[j]);
        }
    }
}

// ---------------------------------------------------------------------------
// 5) output projection + LayerNorm + residual, L/R fused (blockIdx.y)
//    A fragments fully register-prefetched; Bt issue-early/write-late (T14)
// ---------------------------------------------------------------------------
__launch_bounds__(256)
__global__ void proj_ln(const unsigned short* __restrict__ AOl,
                        const unsigned short* __restrict__ AOr,
                        const unsigned short* __restrict__ Wpt,
                        const float* __restrict__ bp,
                        const float* __restrict__ ln_g, const float* __restrict__ ln_b,
                        const float* __restrict__ rn_g, const float* __restrict__ rn_b,
                        const float* __restrict__ xl, const float* __restrict__ xr,
                        float* __restrict__ out) {
    __shared__ unsigned short Bt[2][256][40];

    const int sel = blockIdx.y;
    const unsigned short* AO = sel ? AOr : AOl;
    const float* gamma = sel ? rn_g : ln_g;
    const float* beta  = sel ? rn_b : ln_b;
    const float* xres  = sel ? xr : xl;
    float* o = out + (size_t)sel * 8192 * 256;

    const int tid = threadIdx.x;
    const int lane = tid & 63, wv = tid >> 6;
    const int a = lane & 15, g = lane >> 4;
    const int r0 = blockIdx.x * 64;

    // all 8 A-fragments into registers up front (rows fixed per thread)
    const unsigned short* asrc = AO + (size_t)(r0 + wv * 16 + a) * 256 + g * 8;
    short8 af[8];
#pragma unroll
    for (int ks = 0; ks < 8; ++ks) af[ks] = *(const short8*)(asrc + ks * 32);

    const unsigned short* wsrc = Wpt + (size_t)tid * 256;
    short8 st[4];
#pragma unroll
    for (int i = 0; i < 4; ++i) st[i] = *(const short8*)(wsrc + i * 8);
#pragma unroll
    for (int i = 0; i < 4; ++i) *(short8*)&Bt[0][tid][i * 8] = st[i];
#pragma unroll
    for (int i = 0; i < 4; ++i) st[i] = *(const short8*)(wsrc + 32 + i * 8);

    const f32x4 fz = {0.f, 0.f, 0.f, 0.f};
    f32x4 acc[16];
#pragma unroll
    for (int cf = 0; cf < 16; ++cf) acc[cf] = fz;

    __syncthreads();

#pragma unroll
    for (int ks = 0; ks < 8; ++ks) {
        const int b = ks & 1;
        if (ks < 7) {
#pragma unroll
            for (int i = 0; i < 4; ++i) *(short8*)&Bt[b ^ 1][tid][i * 8] = st[i];
            if (ks < 6) {
#pragma unroll
                for (int i = 0; i < 4; ++i)
                    st[i] = *(const short8*)(wsrc + (ks + 2) * 32 + i * 8);
            }
        }
#pragma unroll
        for (int cf = 0; cf < 16; ++cf) {
            const short8 bfr = *(const short8*)&Bt[b][cf * 16 + a][g * 8];
            acc[cf] = mfma16(af[ks], bfr, acc[cf]);
        }
        __syncthreads();
    }

    float bb[16], gg[16], be[16];
#pragma unroll
    for (int cf = 0; cf < 16; ++cf) {
        const int c = cf * 16 + a;
        bb[cf] = bp[c]; gg[cf] = gamma[c]; be[cf] = beta[c];
    }
#pragma unroll
    for (int r = 0; r < 4; ++r) {
        float y[16];
        float s1 = 0.f, s2 = 0.f;
#pragma unroll
        for (int cf = 0; cf < 16; ++cf) {
            y[cf] = acc[cf][r] + bb[cf];
            s1 += y[cf];
            s2 += y[cf] * y[cf];
        }
#pragma unroll
        for (int mask = 1; mask <= 8; mask <<= 1) {
            s1 += __shfl_xor(s1, mask);
            s2 += __shfl_xor(s2, mask);
        }
        const float mu = s1 * (1.0f / 256.0f);
        const float var = s2 * (1.0f / 256.0f) - mu * mu;
        const float rstd = rsqrtf(var + 1e-5f);
        const int R = r0 + wv * 16 + g * 4 + r;
#pragma unroll
        for (int cf = 0; cf < 16; ++cf) {
            const int c = cf * 16 + a;
            o[(size_t)R * 256 + c] =
                (y[cf] - mu) * rstd * gg[cf] + be[cf] + xres[(size_t)R * 256 + c];
        }
    }
}

// ---------------------------------------------------------------------------
extern "C" void kernel_launch(void* const* d_in, const int* in_sizes, int n_in,
                              void* d_out, int out_size, void* d_ws, size_t ws_size,
                              hipStream_t stream) {
    const float* x_l  = (const float*)d_in[0];
    const float* x_r  = (const float*)d_in[1];
    const float* Wq   = (const float*)d_in[2];
    const float* bq   = (const float*)d_in[3];
    const float* Wk   = (const float*)d_in[4];
    const float* bk   = (const float*)d_in[5];
    const float* Wv   = (const float*)d_in[6];
    const float* bv   = (const float*)d_in[7];
    const float* Wp   = (const float*)d_in[8];
    const float* bp   = (const float*)d_in[9];
    const float* ln_g = (const float*)d_in[10];
    const float* ln_b = (const float*)d_in[11];
    const float* rn_g = (const float*)d_in[12];
    const float* rn_b = (const float*)d_in[13];

    const size_t SZ_TOK = (size_t)8192 * 256;

    unsigned short* xl_bf = (unsigned short*)d_ws;
    unsigned short* xr_bf = xl_bf + SZ_TOK;
    unsigned short* xd_bf = xr_bf + SZ_TOK;
    unsigned short* Qg    = xd_bf + SZ_TOK;
    unsigned short* Kg    = Qg + SZ_TOK;
    unsigned short* Vtg   = Kg + SZ_TOK;
    unsigned short* Wqt   = Vtg + SZ_TOK;
    unsigned short* Wkt   = Wqt + 65536;
    unsigned short* Wvt   = Wkt + 65536;
    unsigned short* Wpt   = Wvt + 65536;
    unsigned short* AOl   = xl_bf;   // qkv_gemm (last reader of xl) precedes pass1
    unsigned short* AOr   = xr_bf;
    unsigned short* Vs    = xd_bf;   // xd dead after qkv_gemm
    float* out = (float*)d_out;

    prep_all<<<3072, 256, 0, stream>>>(x_l, x_r, Wq, Wk, Wv, Wp,
                                       xl_bf, xr_bf, xd_bf, Wqt, Wkt, Wvt, Wpt);
    qkv_gemm<<<dim3(64, 4, 3), 256, 0, stream>>>(xl_bf, xr_bf, xd_bf,
                                                 Wqt, Wkt, Wvt, bq, bk, bv, Qg, Kg, Vtg);
    attn_pass1<<<512, 512, 0, stream>>>(Qg, Kg, Vtg, AOl, Vs);
    attn_pass2<<<512, 512, 0, stream>>>(Qg, Kg, Vs, AOr);
    proj_ln<<<dim3(128, 2), 256, 0, stream>>>(AOl, AOr, Wpt, bp,
                                              ln_g, ln_b, rn_g, rn_b, x_l, x_r, out);
}

// Round 9
// 93.582 us; speedup vs baseline: 1.2184x; 1.2184x over previous
//
#include <hip/hip_runtime.h>
#include <math.h>

// ---------------------------------------------------------------------------
// BiMultiHeadAttention fused pipeline (MI355X / gfx950)
//   B=4 N=2048 E=256 H=8 D=32   (bh = B*H = 32 heads total)
//
// Round 9 (clean revert to validated pieces):
//   - attn_pass1/attn_pass2: EXACT round-5 kernels (single acc, fixed tile
//     order, no setprio, no swizzle) — last config where both outputs passed
//   - qkv_gemm / proj_ln: round-6 versions (reg-direct A operands; validated
//     correct in round 6)
//   - rounds 7/8 failed identically (out_r absmax 0.445) with the
//     {single-acc + stagger + setprio} combo; pieces individually fine,
//     combination toxic -> shelved pending isolated A/B
// ---------------------------------------------------------------------------

typedef __attribute__((ext_vector_type(8))) short short8;   // 8 bf16 (4 VGPR)
typedef __attribute__((ext_vector_type(4))) float f32x4;
typedef __attribute__((ext_vector_type(16))) float f32x16;
typedef __attribute__((ext_vector_type(4))) unsigned short u16x4;

union FragU { unsigned int u[4]; short8 s8; };

__device__ __forceinline__ unsigned short bf16_rn(float f) {
    union { float f; unsigned int u; } c; c.f = f;
    return (unsigned short)((c.u + 0x7FFFu + ((c.u >> 16) & 1u)) >> 16);
}
__device__ __forceinline__ float b2f(unsigned short u) {
    union { unsigned int i; float f; } c; c.i = ((unsigned int)u) << 16;
    return c.f;
}

#if __has_builtin(__builtin_amdgcn_exp2f)
__device__ __forceinline__ float fexp2(float x) { return __builtin_amdgcn_exp2f(x); }
#else
__device__ __forceinline__ float fexp2(float x) { return exp2f(x); }
#endif

__device__ __forceinline__ f32x4 mfma16(short8 a, short8 b, f32x4 c) {
    return __builtin_amdgcn_mfma_f32_16x16x32_bf16(a, b, c, 0, 0, 0);
}
__device__ __forceinline__ f32x16 mfma32(short8 a, short8 b, f32x16 c) {
    return __builtin_amdgcn_mfma_f32_32x32x16_bf16(a, b, c, 0, 0, 0);
}

__device__ __forceinline__ void plswap(unsigned int& x, unsigned int& y) {
    asm("v_permlane32_swap_b32 %0, %1" : "+v"(x), "+v"(y));
}

// S^T regs (k-local = (j&3)+8*(j>>2)+4*hi) packed as w[m]=(p[2m],p[2m+1]) ->
// one 16-row chunk of an MFMA operand fragment (contract elems hi*8+{0..7}).
__device__ __forceinline__ short8 pfrag(unsigned int w0, unsigned int w1,
                                        unsigned int w2, unsigned int w3) {
    plswap(w0, w2);
    plswap(w1, w3);
    FragU fu;
    fu.u[0] = w0; fu.u[1] = w1; fu.u[2] = w2; fu.u[3] = w3;
    return fu.s8;
}

// ---------------------------------------------------------------------------
// 1) merged prep: blocks [0,2048) convert x streams; [2048,3072) transpose W
// ---------------------------------------------------------------------------
__global__ void prep_all(const float* __restrict__ xl, const float* __restrict__ xr,
                         const float* __restrict__ Wq, const float* __restrict__ Wk,
                         const float* __restrict__ Wv, const float* __restrict__ Wp,
                         unsigned short* __restrict__ xlb, unsigned short* __restrict__ xrb,
                         unsigned short* __restrict__ xdb,
                         unsigned short* __restrict__ Wqt, unsigned short* __restrict__ Wkt,
                         unsigned short* __restrict__ Wvt, unsigned short* __restrict__ Wpt) {
    const int bid = blockIdx.x;
    if (bid < 2048) {
        const size_t i = ((size_t)bid * 256 + threadIdx.x) * 4;
        const float4 A = *(const float4*)(xl + i);
        const float4 Bv = *(const float4*)(xr + i);
        u16x4 pa = { bf16_rn(A.x), bf16_rn(A.y), bf16_rn(A.z), bf16_rn(A.w) };
        u16x4 pb = { bf16_rn(Bv.x), bf16_rn(Bv.y), bf16_rn(Bv.z), bf16_rn(Bv.w) };
        u16x4 pd = { bf16_rn(A.x - Bv.x), bf16_rn(A.y - Bv.y),
                     bf16_rn(A.z - Bv.z), bf16_rn(A.w - Bv.w) };
        *(u16x4*)(xlb + i) = pa;
        *(u16x4*)(xrb + i) = pb;
        *(u16x4*)(xdb + i) = pd;
    } else {
        const int gid = (bid - 2048) * 256 + threadIdx.x;   // 0 .. 262143
        const int m = gid >> 16;
        const int idx = gid & 65535;
        const int k = idx >> 8, n = idx & 255;
        const float* W = (m == 0) ? Wq : (m == 1) ? Wk : (m == 2) ? Wv : Wp;
        unsigned short* Wt = (m == 0) ? Wqt : (m == 1) ? Wkt : (m == 2) ? Wvt : Wpt;
        Wt[n * 256 + k] = bf16_rn(W[(size_t)k * 256 + n]);
    }
}

// ---------------------------------------------------------------------------
// 2) QKV projection GEMM: [8192,256] x [256,256] + bias, 3 outputs (z-dim)
//    A register-direct (1-step prefetch), Bt dbuf in LDS  [round-6, validated]
// ---------------------------------------------------------------------------
__launch_bounds__(256)
__global__ void qkv_gemm(const unsigned short* __restrict__ xlb,
                         const unsigned short* __restrict__ xrb,
                         const unsigned short* __restrict__ xdb,
                         const unsigned short* __restrict__ Wqt,
                         const unsigned short* __restrict__ Wkt,
                         const unsigned short* __restrict__ Wvt,
                         const float* __restrict__ bq, const float* __restrict__ bk,
                         const float* __restrict__ bv,
                         unsigned short* __restrict__ Qg, unsigned short* __restrict__ Kg,
                         unsigned short* __restrict__ Vtg) {
    const int z = blockIdx.z;
    const unsigned short* A  = (z == 0) ? xlb : (z == 1) ? xrb : xdb;
    const unsigned short* Wt = (z == 0) ? Wqt : (z == 1) ? Wkt : Wvt;
    const float* bias        = (z == 0) ? bq  : (z == 1) ? bk  : bv;

    __shared__ unsigned short Bt[2][64][40];

    const int tid = threadIdx.x;
    const int lane = tid & 63, wv = tid >> 6;
    const int a = lane & 15, g = lane >> 4;
    const int wr = wv >> 1, wc = wv & 1;
    const int r0 = blockIdx.x * 128;
    const int c0 = blockIdx.y * 64;

    const f32x4 fz = {0.f, 0.f, 0.f, 0.f};
    f32x4 acc[4][2];
#pragma unroll
    for (int f = 0; f < 4; ++f)
#pragma unroll
        for (int t = 0; t < 2; ++t) acc[f][t] = fz;

    const int brow = tid >> 2, boff = (tid & 3) * 8;
    const unsigned short* bsrc = Wt + (size_t)(c0 + brow) * 256 + boff;
    const unsigned short* abase = A + (size_t)(r0 + wr * 64 + a) * 256 + g * 8;

    short8 afA[4], afB[4];
#pragma unroll
    for (int f = 0; f < 4; ++f) afA[f] = *(const short8*)(abase + f * 16 * 256);
    *(short8*)&Bt[0][brow][boff] = *(const short8*)bsrc;
    __syncthreads();

#pragma unroll
    for (int ks = 0; ks < 8; ++ks) {
        const int b = ks & 1;
        const short8* afc = (ks & 1) ? afB : afA;
        short8* afn = (ks & 1) ? afA : afB;
        if (ks < 7) {
            *(short8*)&Bt[b ^ 1][brow][boff] = *(const short8*)(bsrc + (ks + 1) * 32);
#pragma unroll
            for (int f = 0; f < 4; ++f)
                afn[f] = *(const short8*)(abase + f * 16 * 256 + (ks + 1) * 32);
        }
        short8 bfr[2];
#pragma unroll
        for (int t = 0; t < 2; ++t) bfr[t] = *(const short8*)&Bt[b][wc * 32 + t * 16 + a][g * 8];
#pragma unroll
        for (int f = 0; f < 4; ++f)
#pragma unroll
            for (int t = 0; t < 2; ++t) acc[f][t] = mfma16(afc[f], bfr[t], acc[f][t]);
        __syncthreads();
    }

    const float scq = 0.17677669529663687f * 1.4426950408889634f;
#pragma unroll
    for (int t = 0; t < 2; ++t) {
        const int C = c0 + wc * 32 + t * 16 + a;
        const float bb = bias[C];
        const int h = C >> 5, d = C & 31;
#pragma unroll
        for (int f = 0; f < 4; ++f) {
            const int Rb = r0 + wr * 64 + f * 16 + g * 4;
            const int b_ = Rb >> 11, n = Rb & 2047;
            const int bhh = b_ * 8 + h;
            float v[4];
#pragma unroll
            for (int r = 0; r < 4; ++r) {
                v[r] = acc[f][t][r] + bb;
                if (z == 0) v[r] *= scq;
            }
            if (z < 2) {
                unsigned short* dst = ((z == 0) ? Qg : Kg) + (size_t)(bhh * 2048 + n) * 32 + d;
#pragma unroll
                for (int r = 0; r < 4; ++r) dst[(size_t)r * 32] = bf16_rn(v[r]);
            } else {
                u16x4 pk = { bf16_rn(v[0]), bf16_rn(v[1]), bf16_rn(v[2]), bf16_rn(v[3]) };
                *(u16x4*)(Vtg + (size_t)(bhh * 32 + d) * 2048 + n) = pk;
            }
        }
    }
}

// ---------------------------------------------------------------------------
// 3) pass 1: flash attention (exp2 domain, no shift) -> out_l + Vs = V/l
//    EXACT round-5 kernel: 8 waves qi/z, 64-k phases, 4 LDS tile buffers.
// ---------------------------------------------------------------------------
#define P1_TILE(SB)                                                             \
    {                                                                           \
        const short8 ck0 = *(const short8*)((SB) + ro);                         \
        const short8 ck1 = *(const short8*)((SB) + 512 + ro);                   \
        const short8 cv0 = *(const short8*)((SB) + 1024 + ro);                  \
        const short8 cv1 = *(const short8*)((SB) + 1536 + ro);                  \
        f32x16 s = {};                                                          \
        s = mfma32(ck0, qf0, s);                                                \
        s = mfma32(ck1, qf1, s);                                                \
        float p[16];                                                            \
        _Pragma("unroll") for (int j = 0; j < 16; ++j) p[j] = fexp2(s[j]);      \
        l_run += (((p[0] + p[1]) + (p[2] + p[3])) + ((p[4] + p[5]) + (p[6] + p[7]))) \
               + (((p[8] + p[9]) + (p[10] + p[11])) + ((p[12] + p[13]) + (p[14] + p[15]))); \
        unsigned int w[8];                                                      \
        _Pragma("unroll") for (int mm = 0; mm < 8; ++mm)                        \
            asm("v_cvt_pk_bf16_f32 %0, %1, %2"                                  \
                : "=v"(w[mm]) : "v"(p[2 * mm]), "v"(p[2 * mm + 1]));            \
        acc = mfma32(cv0, pfrag(w[0], w[1], w[2], w[3]), acc);                  \
        acc = mfma32(cv1, pfrag(w[4], w[5], w[6], w[7]), acc);                  \
    }

__launch_bounds__(512, 4)
__global__ void attn_pass1(const unsigned short* __restrict__ Qg,
                           const unsigned short* __restrict__ Kg,
                           const unsigned short* __restrict__ Vtg,
                           unsigned short* __restrict__ AOl,
                           unsigned short* __restrict__ Vsg) {
    __shared__ unsigned short ST[2][2][2][2][2][64][8];  // [z][pbuf][sub][kv][c][slot][e] 32KB
    __shared__ float accS[4][16][64];                    // 16KB
    __shared__ float lsumS[4][64];                       // 1KB

    const int f = blockIdx.x;
    const int bh = 4 * (f & 7) + (f >> 7);
    const int qblk = (f >> 3) & 15;
    const int tid = threadIdx.x;
    const int wv = tid >> 6;
    const int qi = wv & 3, z = wv >> 2;
    const int lane = tid & 63, l31 = lane & 31, hi = lane >> 5;
    const int q0 = qblk * 128 + qi * 32;

    const unsigned short* Qb = Qg + (size_t)bh * 2048 * 32;
    const unsigned short* Kb = Kg + (size_t)bh * 2048 * 32;
    const unsigned short* Vb = Vtg + (size_t)bh * 32 * 2048;

    const short8 qf0 = *(const short8*)(Qb + (size_t)(q0 + l31) * 32 + hi * 8);
    const short8 qf1 = *(const short8*)(Qb + (size_t)(q0 + l31) * 32 + 16 + hi * 8);

    // staging geometry: qi<2 -> K rows, qi>=2 -> V rows (16 rows per wave)
    const int kv = qi >> 1;
    const int srow = (qi & 1) * 16 + (lane >> 2);
    const int m = lane & 3;
    unsigned short* wp00 = &ST[z][0][0][kv][m >> 1][srow + 32 * (m & 1)][0];
    unsigned short* wp01 = &ST[z][0][1][kv][m >> 1][srow + 32 * (m & 1)][0];
    unsigned short* wp10 = &ST[z][1][0][kv][m >> 1][srow + 32 * (m & 1)][0];
    unsigned short* wp11 = &ST[z][1][1][kv][m >> 1][srow + 32 * (m & 1)][0];
    const size_t gstep = kv ? 32 : 1024;               // per-tile element step
    const unsigned short* sgb = kv
        ? Vb + (size_t)srow * 2048 + m * 8
        : Kb + (size_t)srow * 32 + m * 8;
    const int zt = z * 32;

    const unsigned short* rb00 = &ST[z][0][0][0][0][0][0];
    const unsigned short* rb01 = &ST[z][0][1][0][0][0][0];
    const unsigned short* rb10 = &ST[z][1][0][0][0][0][0];
    const unsigned short* rb11 = &ST[z][1][1][0][0][0][0];
    const int ro = (l31 + 32 * hi) * 8;

    f32x16 acc = {};
    float l_run = 0.f;

    // prologue: tiles 0,1 -> pbuf0; tiles 2,3 -> regs
    short8 rr0 = *(const short8*)(sgb + (size_t)(zt + 0) * gstep);
    short8 rr1 = *(const short8*)(sgb + (size_t)(zt + 1) * gstep);
    *(short8*)wp00 = rr0;
    *(short8*)wp01 = rr1;
    rr0 = *(const short8*)(sgb + (size_t)(zt + 2) * gstep);
    rr1 = *(const short8*)(sgb + (size_t)(zt + 3) * gstep);
    __syncthreads();

#pragma unroll
    for (int ph = 0; ph < 16; ++ph) {
        const int pb = ph & 1;
        unsigned short* wA = pb ? wp00 : wp10;
        unsigned short* wB = pb ? wp01 : wp11;
        const unsigned short* rA = pb ? rb10 : rb00;
        const unsigned short* rB = pb ? rb11 : rb01;
        if (ph < 15) { *(short8*)wA = rr0; *(short8*)wB = rr1; }
        if (ph < 14) {
            rr0 = *(const short8*)(sgb + (size_t)(zt + 2 * ph + 4) * gstep);
            rr1 = *(const short8*)(sgb + (size_t)(zt + 2 * ph + 5) * gstep);
        }
        P1_TILE(rA)
        P1_TILE(rB)
        __syncthreads();
    }

    float lsum = l_run + __shfl_xor(l_run, 32);

    if (z == 1) {
#pragma unroll
        for (int j = 0; j < 16; ++j) accS[qi][j][lane] = acc[j];
        lsumS[qi][lane] = lsum;
    }
    __syncthreads();
    if (z == 0) {
        lsum += lsumS[qi][lane];
        const float rl = 1.0f / lsum;
#pragma unroll
        for (int j = 0; j < 16; ++j) acc[j] += accS[qi][j][lane];

        const int b_ = bh >> 3, h = bh & 7;
        const int q = q0 + l31;
        unsigned short* dst = AOl + (size_t)(b_ * 2048 + q) * 256 + h * 32;
#pragma unroll
        for (int g2 = 0; g2 < 4; ++g2) {
            u16x4 pk = { bf16_rn(acc[4 * g2 + 0] * rl), bf16_rn(acc[4 * g2 + 1] * rl),
                         bf16_rn(acc[4 * g2 + 2] * rl), bf16_rn(acc[4 * g2 + 3] * rl) };
            *(u16x4*)(dst + 8 * g2 + 4 * hi) = pk;
        }
        if (hi == 0) lsumS[qi][l31] = rl;   // rl for column q0+l31
    }
    __syncthreads();
    if (z == 1) {
        // scale V columns [q0, q0+32) by rl: lane (l31,hi) -> d=l31, 16 cols
        const int cb = hi * 16;
        float il[16];
#pragma unroll
        for (int e = 0; e < 16; e += 4) {
            const float4 v4 = *(const float4*)&lsumS[qi][cb + e];
            il[e] = v4.x; il[e + 1] = v4.y; il[e + 2] = v4.z; il[e + 3] = v4.w;
        }
        const unsigned short* vsrc = Vb + (size_t)l31 * 2048 + q0 + cb;
        unsigned short* vdst = Vsg + (size_t)bh * 32 * 2048 + (size_t)l31 * 2048 + q0 + cb;
#pragma unroll
        for (int c4 = 0; c4 < 4; ++c4) {
            const u16x4 vv = *(const u16x4*)(vsrc + c4 * 4);
            u16x4 o = { bf16_rn(b2f(vv.x) * il[c4 * 4 + 0]),
                        bf16_rn(b2f(vv.y) * il[c4 * 4 + 1]),
                        bf16_rn(b2f(vv.z) * il[c4 * 4 + 2]),
                        bf16_rn(b2f(vv.w) * il[c4 * 4 + 3]) };
            *(u16x4*)(vdst + c4 * 4) = o;
        }
    }
}

// ---------------------------------------------------------------------------
// 4) pass 2: out_r = exp2(S)^T @ Vs  (Vs pre-normalized). EXACT round-5.
// ---------------------------------------------------------------------------
#define P2_TILE(SB)                                                             \
    {                                                                           \
        const short8 cq0 = *(const short8*)((SB) + ro);                         \
        const short8 cq1 = *(const short8*)((SB) + 512 + ro);                   \
        const short8 cv0 = *(const short8*)((SB) + 1024 + ro);                  \
        const short8 cv1 = *(const short8*)((SB) + 1536 + ro);                  \
        f32x16 s = {};                                                          \
        s = mfma32(cq0, kf0, s);                                                \
        s = mfma32(cq1, kf1, s);                                                \
        float p[16];                                                            \
        _Pragma("unroll") for (int j = 0; j < 16; ++j) p[j] = fexp2(s[j]);      \
        unsigned int w[8];                                                      \
        _Pragma("unroll") for (int mm = 0; mm < 8; ++mm)                        \
            asm("v_cvt_pk_bf16_f32 %0, %1, %2"                                  \
                : "=v"(w[mm]) : "v"(p[2 * mm]), "v"(p[2 * mm + 1]));            \
        acc = mfma32(pfrag(w[0], w[1], w[2], w[3]), cv0, acc);                  \
        acc = mfma32(pfrag(w[4], w[5], w[6], w[7]), cv1, acc);                  \
    }

__launch_bounds__(512, 4)
__global__ void attn_pass2(const unsigned short* __restrict__ Qg,
                           const unsigned short* __restrict__ Kg,
                           const unsigned short* __restrict__ Vsg,
                           unsigned short* __restrict__ AOr) {
    __shared__ unsigned short ST[2][2][2][2][2][64][8];
    __shared__ float accS[4][16][64];

    const int f = blockIdx.x;
    const int bh = 4 * (f & 7) + (f >> 7);
    const int kblk = (f >> 3) & 15;
    const int tid = threadIdx.x;
    const int wv = tid >> 6;
    const int ki = wv & 3, z = wv >> 2;
    const int lane = tid & 63, l31 = lane & 31, hi = lane >> 5;
    const int k0 = kblk * 128 + ki * 32;

    const unsigned short* Qb = Qg + (size_t)bh * 2048 * 32;
    const unsigned short* Kb = Kg + (size_t)bh * 2048 * 32;
    const unsigned short* Vb = Vsg + (size_t)bh * 32 * 2048;

    const short8 kf0 = *(const short8*)(Kb + (size_t)(k0 + l31) * 32 + hi * 8);
    const short8 kf1 = *(const short8*)(Kb + (size_t)(k0 + l31) * 32 + 16 + hi * 8);

    const int kv = ki >> 1;
    const int srow = (ki & 1) * 16 + (lane >> 2);
    const int m = lane & 3;
    unsigned short* wp00 = &ST[z][0][0][kv][m >> 1][srow + 32 * (m & 1)][0];
    unsigned short* wp01 = &ST[z][0][1][kv][m >> 1][srow + 32 * (m & 1)][0];
    unsigned short* wp10 = &ST[z][1][0][kv][m >> 1][srow + 32 * (m & 1)][0];
    unsigned short* wp11 = &ST[z][1][1][kv][m >> 1][srow + 32 * (m & 1)][0];
    const size_t gstep = kv ? 32 : 1024;
    const unsigned short* sgb = kv
        ? Vb + (size_t)srow * 2048 + m * 8
        : Qb + (size_t)srow * 32 + m * 8;
    const int zt = z * 32;

    const unsigned short* rb00 = &ST[z][0][0][0][0][0][0];
    const unsigned short* rb01 = &ST[z][0][1][0][0][0][0];
    const unsigned short* rb10 = &ST[z][1][0][0][0][0][0];
    const unsigned short* rb11 = &ST[z][1][1][0][0][0][0];
    const int ro = (l31 + 32 * hi) * 8;

    f32x16 acc = {};

    short8 rr0 = *(const short8*)(sgb + (size_t)(zt + 0) * gstep);
    short8 rr1 = *(const short8*)(sgb + (size_t)(zt + 1) * gstep);
    *(short8*)wp00 = rr0;
    *(short8*)wp01 = rr1;
    rr0 = *(const short8*)(sgb + (size_t)(zt + 2) * gstep);
    rr1 = *(const short8*)(sgb + (size_t)(zt + 3) * gstep);
    __syncthreads();

#pragma unroll
    for (int ph = 0; ph < 16; ++ph) {
        const int pb = ph & 1;
        unsigned short* wA = pb ? wp00 : wp10;
        unsigned short* wB = pb ? wp01 : wp11;
        const unsigned short* rA = pb ? rb10 : rb00;
        const unsigned short* rB = pb ? rb11 : rb01;
        if (ph < 15) { *(short8*)wA = rr0; *(short8*)wB = rr1; }
        if (ph < 14) {
            rr0 = *(const short8*)(sgb + (size_t)(zt + 2 * ph + 4) * gstep);
            rr1 = *(const short8*)(sgb + (size_t)(zt + 2 * ph + 5) * gstep);
        }
        P2_TILE(rA)
        P2_TILE(rB)
        __syncthreads();
    }

    if (z == 1) {
#pragma unroll
        for (int j = 0; j < 16; ++j) accS[ki][j][lane] = acc[j];
    }
    __syncthreads();
    if (z == 0) {
#pragma unroll
        for (int j = 0; j < 16; ++j) acc[j] += accS[ki][j][lane];

        const int b_ = bh >> 3, h = bh & 7;
#pragma unroll
        for (int j = 0; j < 16; ++j) {
            const int krow = k0 + (j & 3) + 8 * (j >> 2) + 4 * hi;
            AOr[(size_t)(b_ * 2048 + krow) * 256 + h * 32 + l31] = bf16_rn(acc[j]);
        }
    }
}

// ---------------------------------------------------------------------------
// 5) output projection + LayerNorm + residual, L/R fused (blockIdx.y)
//    A fragments fully register-prefetched; Bt issue-early/write-late (T14)
// ---------------------------------------------------------------------------
__launch_bounds__(256)
__global__ void proj_ln(const unsigned short* __restrict__ AOl,
                        const unsigned short* __restrict__ AOr,
                        const unsigned short* __restrict__ Wpt,
                        const float* __restrict__ bp,
                        const float* __restrict__ ln_g, const float* __restrict__ ln_b,
                        const float* __restrict__ rn_g, const float* __restrict__ rn_b,
                        const float* __restrict__ xl, const float* __restrict__ xr,
                        float* __restrict__ out) {
    __shared__ unsigned short Bt[2][256][40];

    const int sel = blockIdx.y;
    const unsigned short* AO = sel ? AOr : AOl;
    const float* gamma = sel ? rn_g : ln_g;
    const float* beta  = sel ? rn_b : ln_b;
    const float* xres  = sel ? xr : xl;
    float* o = out + (size_t)sel * 8192 * 256;

    const int tid = threadIdx.x;
    const int lane = tid & 63, wv = tid >> 6;
    const int a = lane & 15, g = lane >> 4;
    const int r0 = blockIdx.x * 64;

    // all 8 A-fragments into registers up front (rows fixed per thread)
    const unsigned short* asrc = AO + (size_t)(r0 + wv * 16 + a) * 256 + g * 8;
    short8 af[8];
#pragma unroll
    for (int ks = 0; ks < 8; ++ks) af[ks] = *(const short8*)(asrc + ks * 32);

    const unsigned short* wsrc = Wpt + (size_t)tid * 256;
    short8 st[4];
#pragma unroll
    for (int i = 0; i < 4; ++i) st[i] = *(const short8*)(wsrc + i * 8);
#pragma unroll
    for (int i = 0; i < 4; ++i) *(short8*)&Bt[0][tid][i * 8] = st[i];
#pragma unroll
    for (int i = 0; i < 4; ++i) st[i] = *(const short8*)(wsrc + 32 + i * 8);

    const f32x4 fz = {0.f, 0.f, 0.f, 0.f};
    f32x4 acc[16];
#pragma unroll
    for (int cf = 0; cf < 16; ++cf) acc[cf] = fz;

    __syncthreads();

#pragma unroll
    for (int ks = 0; ks < 8; ++ks) {
        const int b = ks & 1;
        if (ks < 7) {
#pragma unroll
            for (int i = 0; i < 4; ++i) *(short8*)&Bt[b ^ 1][tid][i * 8] = st[i];
            if (ks < 6) {
#pragma unroll
                for (int i = 0; i < 4; ++i)
                    st[i] = *(const short8*)(wsrc + (ks + 2) * 32 + i * 8);
            }
        }
#pragma unroll
        for (int cf = 0; cf < 16; ++cf) {
            const short8 bfr = *(const short8*)&Bt[b][cf * 16 + a][g * 8];
            acc[cf] = mfma16(af[ks], bfr, acc[cf]);
        }
        __syncthreads();
    }

    float bb[16], gg[16], be[16];
#pragma unroll
    for (int cf = 0; cf < 16; ++cf) {
        const int c = cf * 16 + a;
        bb[cf] = bp[c]; gg[cf] = gamma[c]; be[cf] = beta[c];
    }
#pragma unroll
    for (int r = 0; r < 4; ++r) {
        float y[16];
        float s1 = 0.f, s2 = 0.f;
#pragma unroll
        for (int cf = 0; cf < 16; ++cf) {
            y[cf] = acc[cf][r] + bb[cf];
            s1 += y[cf];
            s2 += y[cf] * y[cf];
        }
#pragma unroll
        for (int mask = 1; mask <= 8; mask <<= 1) {
            s1 += __shfl_xor(s1, mask);
            s2 += __shfl_xor(s2, mask);
        }
        const float mu = s1 * (1.0f / 256.0f);
        const float var = s2 * (1.0f / 256.0f) - mu * mu;
        const float rstd = rsqrtf(var + 1e-5f);
        const int R = r0 + wv * 16 + g * 4 + r;
#pragma unroll
        for (int cf = 0; cf < 16; ++cf) {
            const int c = cf * 16 + a;
            o[(size_t)R * 256 + c] =
                (y[cf] - mu) * rstd * gg[cf] + be[cf] + xres[(size_t)R * 256 + c];
        }
    }
}

// ---------------------------------------------------------------------------
extern "C" void kernel_launch(void* const* d_in, const int* in_sizes, int n_in,
                              void* d_out, int out_size, void* d_ws, size_t ws_size,
                              hipStream_t stream) {
    const float* x_l  = (const float*)d_in[0];
    const float* x_r  = (const float*)d_in[1];
    const float* Wq   = (const float*)d_in[2];
    const float* bq   = (const float*)d_in[3];
    const float* Wk   = (const float*)d_in[4];
    const float* bk   = (const float*)d_in[5];
    const float* Wv   = (const float*)d_in[6];
    const float* bv   = (const float*)d_in[7];
    const float* Wp   = (const float*)d_in[8];
    const float* bp   = (const float*)d_in[9];
    const float* ln_g = (const float*)d_in[10];
    const float* ln_b = (const float*)d_in[11];
    const float* rn_g = (const float*)d_in[12];
    const float* rn_b = (const float*)d_in[13];

    const size_t SZ_TOK = (size_t)8192 * 256;

    unsigned short* xl_bf = (unsigned short*)d_ws;
    unsigned short* xr_bf = xl_bf + SZ_TOK;
    unsigned short* xd_bf = xr_bf + SZ_TOK;
    unsigned short* Qg    = xd_bf + SZ_TOK;
    unsigned short* Kg    = Qg + SZ_TOK;
    unsigned short* Vtg   = Kg + SZ_TOK;
    unsigned short* Wqt   = Vtg + SZ_TOK;
    unsigned short* Wkt   = Wqt + 65536;
    unsigned short* Wvt   = Wkt + 65536;
    unsigned short* Wpt   = Wvt + 65536;
    unsigned short* AOl   = xl_bf;   // qkv_gemm (last reader of xl) precedes pass1
    unsigned short* AOr   = xr_bf;
    unsigned short* Vs    = xd_bf;   // xd dead after qkv_gemm
    float* out = (float*)d_out;

    prep_all<<<3072, 256, 0, stream>>>(x_l, x_r, Wq, Wk, Wv, Wp,
                                       xl_bf, xr_bf, xd_bf, Wqt, Wkt, Wvt, Wpt);
    qkv_gemm<<<dim3(64, 4, 3), 256, 0, stream>>>(xl_bf, xr_bf, xd_bf,
                                                 Wqt, Wkt, Wvt, bq, bk, bv, Qg, Kg, Vtg);
    attn_pass1<<<512, 512, 0, stream>>>(Qg, Kg, Vtg, AOl, Vs);
    attn_pass2<<<512, 512, 0, stream>>>(Qg, Kg, Vs, AOr);
    proj_ln<<<dim3(128, 2), 256, 0, stream>>>(AOl, AOr, Wpt, bp,
                                              ln_g, ln_b, rn_g, rn_b, x_l, x_r, out);
}

// Round 10
// 87.230 us; speedup vs baseline: 1.3071x; 1.0728x over previous
//
#include <hip/hip_runtime.h>
#include <math.h>

// ---------------------------------------------------------------------------
// BiMultiHeadAttention fused pipeline (MI355X / gfx950)
//   B=4 N=2048 E=256 H=8 D=32   (bh = B*H = 32 heads total)
//
// Round 10 = round 5 (best passing, 90.4us) + ONE change:
//   - proj_ln: 32-row blocks, grid (256,2) -> 2 blocks/CU (was 1), waves 2x2
//     (16-row x 128-col each), LN via cross-wave LDS combine. acc 64->32 VGPR.
//   - qkv_gemm reverted to round-5 LDS-staged A (round-6 reg-direct A was a
//     16-lane x 512B gather -> net -3us, measured round 9 vs 5)
// ---------------------------------------------------------------------------

typedef __attribute__((ext_vector_type(8))) short short8;   // 8 bf16 (4 VGPR)
typedef __attribute__((ext_vector_type(4))) float f32x4;
typedef __attribute__((ext_vector_type(16))) float f32x16;
typedef __attribute__((ext_vector_type(4))) unsigned short u16x4;

union FragU { unsigned int u[4]; short8 s8; };

__device__ __forceinline__ unsigned short bf16_rn(float f) {
    union { float f; unsigned int u; } c; c.f = f;
    return (unsigned short)((c.u + 0x7FFFu + ((c.u >> 16) & 1u)) >> 16);
}
__device__ __forceinline__ float b2f(unsigned short u) {
    union { unsigned int i; float f; } c; c.i = ((unsigned int)u) << 16;
    return c.f;
}

#if __has_builtin(__builtin_amdgcn_exp2f)
__device__ __forceinline__ float fexp2(float x) { return __builtin_amdgcn_exp2f(x); }
#else
__device__ __forceinline__ float fexp2(float x) { return exp2f(x); }
#endif

__device__ __forceinline__ f32x4 mfma16(short8 a, short8 b, f32x4 c) {
    return __builtin_amdgcn_mfma_f32_16x16x32_bf16(a, b, c, 0, 0, 0);
}
__device__ __forceinline__ f32x16 mfma32(short8 a, short8 b, f32x16 c) {
    return __builtin_amdgcn_mfma_f32_32x32x16_bf16(a, b, c, 0, 0, 0);
}

__device__ __forceinline__ void plswap(unsigned int& x, unsigned int& y) {
    asm("v_permlane32_swap_b32 %0, %1" : "+v"(x), "+v"(y));
}

// S^T regs (k-local = (j&3)+8*(j>>2)+4*hi) packed as w[m]=(p[2m],p[2m+1]) ->
// one 16-row chunk of an MFMA operand fragment (contract elems hi*8+{0..7}).
__device__ __forceinline__ short8 pfrag(unsigned int w0, unsigned int w1,
                                        unsigned int w2, unsigned int w3) {
    plswap(w0, w2);
    plswap(w1, w3);
    FragU fu;
    fu.u[0] = w0; fu.u[1] = w1; fu.u[2] = w2; fu.u[3] = w3;
    return fu.s8;
}

// ---------------------------------------------------------------------------
// 1) merged prep: blocks [0,2048) convert x streams; [2048,3072) transpose W
// ---------------------------------------------------------------------------
__global__ void prep_all(const float* __restrict__ xl, const float* __restrict__ xr,
                         const float* __restrict__ Wq, const float* __restrict__ Wk,
                         const float* __restrict__ Wv, const float* __restrict__ Wp,
                         unsigned short* __restrict__ xlb, unsigned short* __restrict__ xrb,
                         unsigned short* __restrict__ xdb,
                         unsigned short* __restrict__ Wqt, unsigned short* __restrict__ Wkt,
                         unsigned short* __restrict__ Wvt, unsigned short* __restrict__ Wpt) {
    const int bid = blockIdx.x;
    if (bid < 2048) {
        const size_t i = ((size_t)bid * 256 + threadIdx.x) * 4;
        const float4 A = *(const float4*)(xl + i);
        const float4 Bv = *(const float4*)(xr + i);
        u16x4 pa = { bf16_rn(A.x), bf16_rn(A.y), bf16_rn(A.z), bf16_rn(A.w) };
        u16x4 pb = { bf16_rn(Bv.x), bf16_rn(Bv.y), bf16_rn(Bv.z), bf16_rn(Bv.w) };
        u16x4 pd = { bf16_rn(A.x - Bv.x), bf16_rn(A.y - Bv.y),
                     bf16_rn(A.z - Bv.z), bf16_rn(A.w - Bv.w) };
        *(u16x4*)(xlb + i) = pa;
        *(u16x4*)(xrb + i) = pb;
        *(u16x4*)(xdb + i) = pd;
    } else {
        const int gid = (bid - 2048) * 256 + threadIdx.x;   // 0 .. 262143
        const int m = gid >> 16;
        const int idx = gid & 65535;
        const int k = idx >> 8, n = idx & 255;
        const float* W = (m == 0) ? Wq : (m == 1) ? Wk : (m == 2) ? Wv : Wp;
        unsigned short* Wt = (m == 0) ? Wqt : (m == 1) ? Wkt : (m == 2) ? Wvt : Wpt;
        Wt[n * 256 + k] = bf16_rn(W[(size_t)k * 256 + n]);
    }
}

// ---------------------------------------------------------------------------
// 2) QKV projection GEMM: [8192,256] x [256,256] + bias, 3 outputs (z-dim)
//    dbuf LDS staging (round-5, validated best)
// ---------------------------------------------------------------------------
__launch_bounds__(256)
__global__ void qkv_gemm(const unsigned short* __restrict__ xlb,
                         const unsigned short* __restrict__ xrb,
                         const unsigned short* __restrict__ xdb,
                         const unsigned short* __restrict__ Wqt,
                         const unsigned short* __restrict__ Wkt,
                         const unsigned short* __restrict__ Wvt,
                         const float* __restrict__ bq, const float* __restrict__ bk,
                         const float* __restrict__ bv,
                         unsigned short* __restrict__ Qg, unsigned short* __restrict__ Kg,
                         unsigned short* __restrict__ Vtg) {
    const int z = blockIdx.z;
    const unsigned short* A  = (z == 0) ? xlb : (z == 1) ? xrb : xdb;
    const unsigned short* Wt = (z == 0) ? Wqt : (z == 1) ? Wkt : Wvt;
    const float* bias        = (z == 0) ? bq  : (z == 1) ? bk  : bv;

    __shared__ unsigned short At[2][128][40];
    __shared__ unsigned short Bt[2][64][40];

    const int tid = threadIdx.x;
    const int lane = tid & 63, wv = tid >> 6;
    const int a = lane & 15, g = lane >> 4;
    const int wr = wv >> 1, wc = wv & 1;
    const int r0 = blockIdx.x * 128;
    const int c0 = blockIdx.y * 64;

    const f32x4 fz = {0.f, 0.f, 0.f, 0.f};
    f32x4 acc[4][2];
#pragma unroll
    for (int f = 0; f < 4; ++f)
#pragma unroll
        for (int t = 0; t < 2; ++t) acc[f][t] = fz;

    const int arow = tid >> 1, aoff = (tid & 1) * 16;
    const int brow = tid >> 2, boff = (tid & 3) * 8;
    const unsigned short* asrc = A + (size_t)(r0 + arow) * 256 + aoff;
    const unsigned short* bsrc = Wt + (size_t)(c0 + brow) * 256 + boff;

#define QKV_STAGE(KS, BUF)                                                      \
    {                                                                           \
        *(short8*)&At[BUF][arow][aoff]     = *(const short8*)(asrc + (KS) * 32); \
        *(short8*)&At[BUF][arow][aoff + 8] = *(const short8*)(asrc + (KS) * 32 + 8); \
        *(short8*)&Bt[BUF][brow][boff]     = *(const short8*)(bsrc + (KS) * 32); \
    }

    QKV_STAGE(0, 0)
    __syncthreads();

#pragma unroll
    for (int ks = 0; ks < 8; ++ks) {
        const int b = ks & 1;
        if (ks < 7) QKV_STAGE(ks + 1, b ^ 1)
        short8 af[4], bfr[2];
#pragma unroll
        for (int f = 0; f < 4; ++f) af[f] = *(const short8*)&At[b][wr * 64 + f * 16 + a][g * 8];
#pragma unroll
        for (int t = 0; t < 2; ++t) bfr[t] = *(const short8*)&Bt[b][wc * 32 + t * 16 + a][g * 8];
#pragma unroll
        for (int f = 0; f < 4; ++f)
#pragma unroll
            for (int t = 0; t < 2; ++t) acc[f][t] = mfma16(af[f], bfr[t], acc[f][t]);
        __syncthreads();
    }
#undef QKV_STAGE

    const float scq = 0.17677669529663687f * 1.4426950408889634f;
#pragma unroll
    for (int t = 0; t < 2; ++t) {
        const int C = c0 + wc * 32 + t * 16 + a;
        const float bb = bias[C];
        const int h = C >> 5, d = C & 31;
#pragma unroll
        for (int f = 0; f < 4; ++f) {
            const int Rb = r0 + wr * 64 + f * 16 + g * 4;
            const int b_ = Rb >> 11, n = Rb & 2047;
            const int bhh = b_ * 8 + h;
            float v[4];
#pragma unroll
            for (int r = 0; r < 4; ++r) {
                v[r] = acc[f][t][r] + bb;
                if (z == 0) v[r] *= scq;
            }
            if (z < 2) {
                unsigned short* dst = ((z == 0) ? Qg : Kg) + (size_t)(bhh * 2048 + n) * 32 + d;
#pragma unroll
                for (int r = 0; r < 4; ++r) dst[(size_t)r * 32] = bf16_rn(v[r]);
            } else {
                u16x4 pk = { bf16_rn(v[0]), bf16_rn(v[1]), bf16_rn(v[2]), bf16_rn(v[3]) };
                *(u16x4*)(Vtg + (size_t)(bhh * 32 + d) * 2048 + n) = pk;
            }
        }
    }
}

// ---------------------------------------------------------------------------
// 3) pass 1: flash attention (exp2 domain, no shift) -> out_l + Vs = V/l
//    EXACT round-5 kernel.
// ---------------------------------------------------------------------------
#define P1_TILE(SB)                                                             \
    {                                                                           \
        const short8 ck0 = *(const short8*)((SB) + ro);                         \
        const short8 ck1 = *(const short8*)((SB) + 512 + ro);                   \
        const short8 cv0 = *(const short8*)((SB) + 1024 + ro);                  \
        const short8 cv1 = *(const short8*)((SB) + 1536 + ro);                  \
        f32x16 s = {};                                                          \
        s = mfma32(ck0, qf0, s);                                                \
        s = mfma32(ck1, qf1, s);                                                \
        float p[16];                                                            \
        _Pragma("unroll") for (int j = 0; j < 16; ++j) p[j] = fexp2(s[j]);      \
        l_run += (((p[0] + p[1]) + (p[2] + p[3])) + ((p[4] + p[5]) + (p[6] + p[7]))) \
               + (((p[8] + p[9]) + (p[10] + p[11])) + ((p[12] + p[13]) + (p[14] + p[15]))); \
        unsigned int w[8];                                                      \
        _Pragma("unroll") for (int mm = 0; mm < 8; ++mm)                        \
            asm("v_cvt_pk_bf16_f32 %0, %1, %2"                                  \
                : "=v"(w[mm]) : "v"(p[2 * mm]), "v"(p[2 * mm + 1]));            \
        acc = mfma32(cv0, pfrag(w[0], w[1], w[2], w[3]), acc);                  \
        acc = mfma32(cv1, pfrag(w[4], w[5], w[6], w[7]), acc);                  \
    }

__launch_bounds__(512, 4)
__global__ void attn_pass1(const unsigned short* __restrict__ Qg,
                           const unsigned short* __restrict__ Kg,
                           const unsigned short* __restrict__ Vtg,
                           unsigned short* __restrict__ AOl,
                           unsigned short* __restrict__ Vsg) {
    __shared__ unsigned short ST[2][2][2][2][2][64][8];  // [z][pbuf][sub][kv][c][slot][e] 32KB
    __shared__ float accS[4][16][64];                    // 16KB
    __shared__ float lsumS[4][64];                       // 1KB

    const int f = blockIdx.x;
    const int bh = 4 * (f & 7) + (f >> 7);
    const int qblk = (f >> 3) & 15;
    const int tid = threadIdx.x;
    const int wv = tid >> 6;
    const int qi = wv & 3, z = wv >> 2;
    const int lane = tid & 63, l31 = lane & 31, hi = lane >> 5;
    const int q0 = qblk * 128 + qi * 32;

    const unsigned short* Qb = Qg + (size_t)bh * 2048 * 32;
    const unsigned short* Kb = Kg + (size_t)bh * 2048 * 32;
    const unsigned short* Vb = Vtg + (size_t)bh * 32 * 2048;

    const short8 qf0 = *(const short8*)(Qb + (size_t)(q0 + l31) * 32 + hi * 8);
    const short8 qf1 = *(const short8*)(Qb + (size_t)(q0 + l31) * 32 + 16 + hi * 8);

    // staging geometry: qi<2 -> K rows, qi>=2 -> V rows (16 rows per wave)
    const int kv = qi >> 1;
    const int srow = (qi & 1) * 16 + (lane >> 2);
    const int m = lane & 3;
    unsigned short* wp00 = &ST[z][0][0][kv][m >> 1][srow + 32 * (m & 1)][0];
    unsigned short* wp01 = &ST[z][0][1][kv][m >> 1][srow + 32 * (m & 1)][0];
    unsigned short* wp10 = &ST[z][1][0][kv][m >> 1][srow + 32 * (m & 1)][0];
    unsigned short* wp11 = &ST[z][1][1][kv][m >> 1][srow + 32 * (m & 1)][0];
    const size_t gstep = kv ? 32 : 1024;               // per-tile element step
    const unsigned short* sgb = kv
        ? Vb + (size_t)srow * 2048 + m * 8
        : Kb + (size_t)srow * 32 + m * 8;
    const int zt = z * 32;

    const unsigned short* rb00 = &ST[z][0][0][0][0][0][0];
    const unsigned short* rb01 = &ST[z][0][1][0][0][0][0];
    const unsigned short* rb10 = &ST[z][1][0][0][0][0][0];
    const unsigned short* rb11 = &ST[z][1][1][0][0][0][0];
    const int ro = (l31 + 32 * hi) * 8;

    f32x16 acc = {};
    float l_run = 0.f;

    // prologue: tiles 0,1 -> pbuf0; tiles 2,3 -> regs
    short8 rr0 = *(const short8*)(sgb + (size_t)(zt + 0) * gstep);
    short8 rr1 = *(const short8*)(sgb + (size_t)(zt + 1) * gstep);
    *(short8*)wp00 = rr0;
    *(short8*)wp01 = rr1;
    rr0 = *(const short8*)(sgb + (size_t)(zt + 2) * gstep);
    rr1 = *(const short8*)(sgb + (size_t)(zt + 3) * gstep);
    __syncthreads();

#pragma unroll
    for (int ph = 0; ph < 16; ++ph) {
        const int pb = ph & 1;
        unsigned short* wA = pb ? wp00 : wp10;
        unsigned short* wB = pb ? wp01 : wp11;
        const unsigned short* rA = pb ? rb10 : rb00;
        const unsigned short* rB = pb ? rb11 : rb01;
        if (ph < 15) { *(short8*)wA = rr0; *(short8*)wB = rr1; }
        if (ph < 14) {
            rr0 = *(const short8*)(sgb + (size_t)(zt + 2 * ph + 4) * gstep);
            rr1 = *(const short8*)(sgb + (size_t)(zt + 2 * ph + 5) * gstep);
        }
        P1_TILE(rA)
        P1_TILE(rB)
        __syncthreads();
    }

    float lsum = l_run + __shfl_xor(l_run, 32);

    if (z == 1) {
#pragma unroll
        for (int j = 0; j < 16; ++j) accS[qi][j][lane] = acc[j];
        lsumS[qi][lane] = lsum;
    }
    __syncthreads();
    if (z == 0) {
        lsum += lsumS[qi][lane];
        const float rl = 1.0f / lsum;
#pragma unroll
        for (int j = 0; j < 16; ++j) acc[j] += accS[qi][j][lane];

        const int b_ = bh >> 3, h = bh & 7;
        const int q = q0 + l31;
        unsigned short* dst = AOl + (size_t)(b_ * 2048 + q) * 256 + h * 32;
#pragma unroll
        for (int g2 = 0; g2 < 4; ++g2) {
            u16x4 pk = { bf16_rn(acc[4 * g2 + 0] * rl), bf16_rn(acc[4 * g2 + 1] * rl),
                         bf16_rn(acc[4 * g2 + 2] * rl), bf16_rn(acc[4 * g2 + 3] * rl) };
            *(u16x4*)(dst + 8 * g2 + 4 * hi) = pk;
        }
        if (hi == 0) lsumS[qi][l31] = rl;   // rl for column q0+l31
    }
    __syncthreads();
    if (z == 1) {
        // scale V columns [q0, q0+32) by rl: lane (l31,hi) -> d=l31, 16 cols
        const int cb = hi * 16;
        float il[16];
#pragma unroll
        for (int e = 0; e < 16; e += 4) {
            const float4 v4 = *(const float4*)&lsumS[qi][cb + e];
            il[e] = v4.x; il[e + 1] = v4.y; il[e + 2] = v4.z; il[e + 3] = v4.w;
        }
        const unsigned short* vsrc = Vb + (size_t)l31 * 2048 + q0 + cb;
        unsigned short* vdst = Vsg + (size_t)bh * 32 * 2048 + (size_t)l31 * 2048 + q0 + cb;
#pragma unroll
        for (int c4 = 0; c4 < 4; ++c4) {
            const u16x4 vv = *(const u16x4*)(vsrc + c4 * 4);
            u16x4 o = { bf16_rn(b2f(vv.x) * il[c4 * 4 + 0]),
                        bf16_rn(b2f(vv.y) * il[c4 * 4 + 1]),
                        bf16_rn(b2f(vv.z) * il[c4 * 4 + 2]),
                        bf16_rn(b2f(vv.w) * il[c4 * 4 + 3]) };
            *(u16x4*)(vdst + c4 * 4) = o;
        }
    }
}

// ---------------------------------------------------------------------------
// 4) pass 2: out_r = exp2(S)^T @ Vs  (Vs pre-normalized). EXACT round-5.
// ---------------------------------------------------------------------------
#define P2_TILE(SB)                                                             \
    {                                                                           \
        const short8 cq0 = *(const short8*)((SB) + ro);                         \
        const short8 cq1 = *(const short8*)((SB) + 512 + ro);                   \
        const short8 cv0 = *(const short8*)((SB) + 1024 + ro);                  \
        const short8 cv1 = *(const short8*)((SB) + 1536 + ro);                  \
        f32x16 s = {};                                                          \
        s = mfma32(cq0, kf0, s);                                                \
        s = mfma32(cq1, kf1, s);                                                \
        float p[16];                                                            \
        _Pragma("unroll") for (int j = 0; j < 16; ++j) p[j] = fexp2(s[j]);      \
        unsigned int w[8];                                                      \
        _Pragma("unroll") for (int mm = 0; mm < 8; ++mm)                        \
            asm("v_cvt_pk_bf16_f32 %0, %1, %2"                                  \
                : "=v"(w[mm]) : "v"(p[2 * mm]), "v"(p[2 * mm + 1]));            \
        acc = mfma32(pfrag(w[0], w[1], w[2], w[3]), cv0, acc);                  \
        acc = mfma32(pfrag(w[4], w[5], w[6], w[7]), cv1, acc);                  \
    }

__launch_bounds__(512, 4)
__global__ void attn_pass2(const unsigned short* __restrict__ Qg,
                           const unsigned short* __restrict__ Kg,
                           const unsigned short* __restrict__ Vsg,
                           unsigned short* __restrict__ AOr) {
    __shared__ unsigned short ST[2][2][2][2][2][64][8];
    __shared__ float accS[4][16][64];

    const int f = blockIdx.x;
    const int bh = 4 * (f & 7) + (f >> 7);
    const int kblk = (f >> 3) & 15;
    const int tid = threadIdx.x;
    const int wv = tid >> 6;
    const int ki = wv & 3, z = wv >> 2;
    const int lane = tid & 63, l31 = lane & 31, hi = lane >> 5;
    const int k0 = kblk * 128 + ki * 32;

    const unsigned short* Qb = Qg + (size_t)bh * 2048 * 32;
    const unsigned short* Kb = Kg + (size_t)bh * 2048 * 32;
    const unsigned short* Vb = Vsg + (size_t)bh * 32 * 2048;

    const short8 kf0 = *(const short8*)(Kb + (size_t)(k0 + l31) * 32 + hi * 8);
    const short8 kf1 = *(const short8*)(Kb + (size_t)(k0 + l31) * 32 + 16 + hi * 8);

    const int kv = ki >> 1;
    const int srow = (ki & 1) * 16 + (lane >> 2);
    const int m = lane & 3;
    unsigned short* wp00 = &ST[z][0][0][kv][m >> 1][srow + 32 * (m & 1)][0];
    unsigned short* wp01 = &ST[z][0][1][kv][m >> 1][srow + 32 * (m & 1)][0];
    unsigned short* wp10 = &ST[z][1][0][kv][m >> 1][srow + 32 * (m & 1)][0];
    unsigned short* wp11 = &ST[z][1][1][kv][m >> 1][srow + 32 * (m & 1)][0];
    const size_t gstep = kv ? 32 : 1024;
    const unsigned short* sgb = kv
        ? Vb + (size_t)srow * 2048 + m * 8
        : Qb + (size_t)srow * 32 + m * 8;
    const int zt = z * 32;

    const unsigned short* rb00 = &ST[z][0][0][0][0][0][0];
    const unsigned short* rb01 = &ST[z][0][1][0][0][0][0];
    const unsigned short* rb10 = &ST[z][1][0][0][0][0][0];
    const unsigned short* rb11 = &ST[z][1][1][0][0][0][0];
    const int ro = (l31 + 32 * hi) * 8;

    f32x16 acc = {};

    short8 rr0 = *(const short8*)(sgb + (size_t)(zt + 0) * gstep);
    short8 rr1 = *(const short8*)(sgb + (size_t)(zt + 1) * gstep);
    *(short8*)wp00 = rr0;
    *(short8*)wp01 = rr1;
    rr0 = *(const short8*)(sgb + (size_t)(zt + 2) * gstep);
    rr1 = *(const short8*)(sgb + (size_t)(zt + 3) * gstep);
    __syncthreads();

#pragma unroll
    for (int ph = 0; ph < 16; ++ph) {
        const int pb = ph & 1;
        unsigned short* wA = pb ? wp00 : wp10;
        unsigned short* wB = pb ? wp01 : wp11;
        const unsigned short* rA = pb ? rb10 : rb00;
        const unsigned short* rB = pb ? rb11 : rb01;
        if (ph < 15) { *(short8*)wA = rr0; *(short8*)wB = rr1; }
        if (ph < 14) {
            rr0 = *(const short8*)(sgb + (size_t)(zt + 2 * ph + 4) * gstep);
            rr1 = *(const short8*)(sgb + (size_t)(zt + 2 * ph + 5) * gstep);
        }
        P2_TILE(rA)
        P2_TILE(rB)
        __syncthreads();
    }

    if (z == 1) {
#pragma unroll
        for (int j = 0; j < 16; ++j) accS[ki][j][lane] = acc[j];
    }
    __syncthreads();
    if (z == 0) {
#pragma unroll
        for (int j = 0; j < 16; ++j) acc[j] += accS[ki][j][lane];

        const int b_ = bh >> 3, h = bh & 7;
#pragma unroll
        for (int j = 0; j < 16; ++j) {
            const int krow = k0 + (j & 3) + 8 * (j >> 2) + 4 * hi;
            AOr[(size_t)(b_ * 2048 + krow) * 256 + h * 32 + l31] = bf16_rn(acc[j]);
        }
    }
}

// ---------------------------------------------------------------------------
// 5) output projection + LayerNorm + residual, L/R fused (blockIdx.y)
//    NEW: 32-row blocks, grid (256,2) -> 2 blocks/CU. Waves 2x2: wr=row half,
//    wc=col half. LN combined across wc pairs via small LDS exchange.
// ---------------------------------------------------------------------------
__launch_bounds__(256)
__global__ void proj_ln(const unsigned short* __restrict__ AOl,
                        const unsigned short* __restrict__ AOr,
                        const unsigned short* __restrict__ Wpt,
                        const float* __restrict__ bp,
                        const float* __restrict__ ln_g, const float* __restrict__ ln_b,
                        const float* __restrict__ rn_g, const float* __restrict__ rn_b,
                        const float* __restrict__ xl, const float* __restrict__ xr,
                        float* __restrict__ out) {
    __shared__ unsigned short At[32][264];
    __shared__ unsigned short Bt[2][256][40];
    __shared__ float lnS[2][2][2][16];   // [wr][wc][s1|s2][row16]

    const int sel = blockIdx.y;
    const unsigned short* AO = sel ? AOr : AOl;
    const float* gamma = sel ? rn_g : ln_g;
    const float* beta  = sel ? rn_b : ln_b;
    const float* xres  = sel ? xr : xl;
    float* o = out + (size_t)sel * 8192 * 256;

    const int tid = threadIdx.x;
    const int lane = tid & 63, wv = tid >> 6;
    const int a = lane & 15, g = lane >> 4;
    const int wr = wv >> 1, wc = wv & 1;
    const int r0 = blockIdx.x * 32;

    {   // stage the 32x256 A block (coalesced)
        const int row = tid >> 3, seg = (tid & 7) * 32;
        const unsigned short* src = AO + (size_t)(r0 + row) * 256 + seg;
#pragma unroll
        for (int i = 0; i < 4; ++i)
            *(short8*)&At[row][seg + i * 8] = *(const short8*)(src + i * 8);
    }
    const unsigned short* wsrc = Wpt + (size_t)tid * 256;
#pragma unroll
    for (int i = 0; i < 4; ++i)
        *(short8*)&Bt[0][tid][i * 8] = *(const short8*)(wsrc + i * 8);

    const f32x4 fz = {0.f, 0.f, 0.f, 0.f};
    f32x4 acc[8];
#pragma unroll
    for (int cf = 0; cf < 8; ++cf) acc[cf] = fz;

    __syncthreads();

#pragma unroll
    for (int ks = 0; ks < 8; ++ks) {
        const int b = ks & 1;
        if (ks < 7) {
#pragma unroll
            for (int i = 0; i < 4; ++i)
                *(short8*)&Bt[b ^ 1][tid][i * 8] =
                    *(const short8*)(wsrc + (ks + 1) * 32 + i * 8);
        }
        const short8 af = *(const short8*)&At[wr * 16 + a][ks * 32 + g * 8];
#pragma unroll
        for (int cf = 0; cf < 8; ++cf) {
            const short8 bfr = *(const short8*)&Bt[b][wc * 128 + cf * 16 + a][g * 8];
            acc[cf] = mfma16(af, bfr, acc[cf]);
        }
        __syncthreads();
    }

    float bb[8], gg[8], be[8];
#pragma unroll
    for (int cf = 0; cf < 8; ++cf) {
        const int c = wc * 128 + cf * 16 + a;
        bb[cf] = bp[c]; gg[cf] = gamma[c]; be[cf] = beta[c];
    }

    // per-row partial LN sums over this wave's 128 cols
    float y[4][8], s1r[4], s2r[4];
#pragma unroll
    for (int r = 0; r < 4; ++r) {
        float s1 = 0.f, s2 = 0.f;
#pragma unroll
        for (int cf = 0; cf < 8; ++cf) {
            const float yv = acc[cf][r] + bb[cf];
            y[r][cf] = yv;
            s1 += yv;
            s2 += yv * yv;
        }
#pragma unroll
        for (int mask = 1; mask <= 8; mask <<= 1) {
            s1 += __shfl_xor(s1, mask);
            s2 += __shfl_xor(s2, mask);
        }
        s1r[r] = s1; s2r[r] = s2;
    }
    if (a == 0) {
#pragma unroll
        for (int r = 0; r < 4; ++r) {
            lnS[wr][wc][0][g * 4 + r] = s1r[r];
            lnS[wr][wc][1][g * 4 + r] = s2r[r];
        }
    }
    __syncthreads();
#pragma unroll
    for (int r = 0; r < 4; ++r) {
        const float s1 = s1r[r] + lnS[wr][wc ^ 1][0][g * 4 + r];
        const float s2 = s2r[r] + lnS[wr][wc ^ 1][1][g * 4 + r];
        const float mu = s1 * (1.0f / 256.0f);
        const float var = s2 * (1.0f / 256.0f) - mu * mu;
        const float rstd = rsqrtf(var + 1e-5f);
        const int R = r0 + wr * 16 + g * 4 + r;
#pragma unroll
        for (int cf = 0; cf < 8; ++cf) {
            const int c = wc * 128 + cf * 16 + a;
            o[(size_t)R * 256 + c] =
                (y[r][cf] - mu) * rstd * gg[cf] + be[cf] + xres[(size_t)R * 256 + c];
        }
    }
}

// ---------------------------------------------------------------------------
extern "C" void kernel_launch(void* const* d_in, const int* in_sizes, int n_in,
                              void* d_out, int out_size, void* d_ws, size_t ws_size,
                              hipStream_t stream) {
    const float* x_l  = (const float*)d_in[0];
    const float* x_r  = (const float*)d_in[1];
    const float* Wq   = (const float*)d_in[2];
    const float* bq   = (const float*)d_in[3];
    const float* Wk   = (const float*)d_in[4];
    const float* bk   = (const float*)d_in[5];
    const float* Wv   = (const float*)d_in[6];
    const float* bv   = (const float*)d_in[7];
    const float* Wp   = (const float*)d_in[8];
    const float* bp   = (const float*)d_in[9];
    const float* ln_g = (const float*)d_in[10];
    const float* ln_b = (const float*)d_in[11];
    const float* rn_g = (const float*)d_in[12];
    const float* rn_b = (const float*)d_in[13];

    const size_t SZ_TOK = (size_t)8192 * 256;

    unsigned short* xl_bf = (unsigned short*)d_ws;
    unsigned short* xr_bf = xl_bf + SZ_TOK;
    unsigned short* xd_bf = xr_bf + SZ_TOK;
    unsigned short* Qg    = xd_bf + SZ_TOK;
    unsigned short* Kg    = Qg + SZ_TOK;
    unsigned short* Vtg   = Kg + SZ_TOK;
    unsigned short* Wqt   = Vtg + SZ_TOK;
    unsigned short* Wkt   = Wqt + 65536;
    unsigned short* Wvt   = Wkt + 65536;
    unsigned short* Wpt   = Wvt + 65536;
    unsigned short* AOl   = xl_bf;   // qkv_gemm (last reader of xl) precedes pass1
    unsigned short* AOr   = xr_bf;
    unsigned short* Vs    = xd_bf;   // xd dead after qkv_gemm
    float* out = (float*)d_out;

    prep_all<<<3072, 256, 0, stream>>>(x_l, x_r, Wq, Wk, Wv, Wp,
                                       xl_bf, xr_bf, xd_bf, Wqt, Wkt, Wvt, Wpt);
    qkv_gemm<<<dim3(64, 4, 3), 256, 0, stream>>>(xl_bf, xr_bf, xd_bf,
                                                 Wqt, Wkt, Wvt, bq, bk, bv, Qg, Kg, Vtg);
    attn_pass1<<<512, 512, 0, stream>>>(Qg, Kg, Vtg, AOl, Vs);
    attn_pass2<<<512, 512, 0, stream>>>(Qg, Kg, Vs, AOr);
    proj_ln<<<dim3(256, 2), 256, 0, stream>>>(AOl, AOr, Wpt, bp,
                                              ln_g, ln_b, rn_g, rn_b, x_l, x_r, out);
}